// Round 2
// baseline (788.009 us; speedup 1.0000x reference)
//
#include <hip/hip_runtime.h>
#include <math.h>

// x: [B=16, C=256, H=128, W=128] fp32; plane = 16384 elems; B*C = 4096 planes
#define PLANE 16384
#define NPLANES 4096
#define NB 16
#define NC 256
#define NR 16
#define GRID 2048   // 2 planes per block

typedef float vfloat4 __attribute__((ext_vector_type(4)));

// Single fused kernel, pipelined via device-scope atomics:
//   phase A: each block pools its 2 planes (same batch), publishes means (release)
//   phase B: last block of each 128-block batch group computes the 256 gates
//            once ready[b]==256, publishes gate flag (release)
//   phase C: every block waits on its batch's gate flag, scales its OWN 2 planes
//            (minimal re-read distance -> best chance of L3/Infinity-Cache hits),
//            NT stores so `out` doesn't evict x from L3.
// Deadlock-free without co-residency: a block only waits on pools of its own
// 128-block group; all pools precede all waits program-order-wise, and retired
// groups free slots for stragglers.
__global__ __launch_bounds__(256, 8) void fused_kernel(
    const float* __restrict__ x,
    const float* __restrict__ w1, const float* __restrict__ b1,
    const float* __restrict__ w2, const float* __restrict__ b2,
    float* __restrict__ out,
    float* __restrict__ mean, float* __restrict__ gate,
    unsigned int* __restrict__ ready, unsigned int* __restrict__ gflag)
{
    const int i   = blockIdx.x;
    const int tid = threadIdx.x;
    const int wave = tid >> 6, lane = tid & 63;
    const int p0 = i * 2;          // 2 consecutive planes, same batch
    const int b  = p0 >> 8;        // batch

    __shared__ float wsum[4];
    __shared__ float hsh[NR];
    __shared__ float msh[NC];

    // ---------------- phase A: pool both planes ----------------
    #pragma unroll
    for (int q = 0; q < 2; ++q) {
        const int p = p0 + q;
        const vfloat4* xp = (const vfloat4*)(x + (size_t)p * PLANE);
        float s = 0.f;
        #pragma unroll
        for (int h = 0; h < 2; ++h) {
            vfloat4 v[8];
            #pragma unroll
            for (int j = 0; j < 8; ++j) v[j] = xp[tid + (h * 8 + j) * 256];
            #pragma unroll
            for (int j = 0; j < 8; ++j) s += (v[j].x + v[j].y) + (v[j].z + v[j].w);
        }
        #pragma unroll
        for (int o = 32; o > 0; o >>= 1) s += __shfl_down(s, o, 64);
        if (lane == 0) wsum[wave] = s;
        __syncthreads();
        if (tid == 0) {
            float m = ((wsum[0] + wsum[1]) + (wsum[2] + wsum[3])) * (1.0f / (float)PLANE);
            __hip_atomic_store(&mean[p], m, __ATOMIC_RELAXED, __HIP_MEMORY_SCOPE_AGENT);
        }
        __syncthreads();   // wsum reuse
    }
    if (tid == 0)
        __hip_atomic_fetch_add(&ready[b], 2u, __ATOMIC_RELEASE, __HIP_MEMORY_SCOPE_AGENT);

    // ---------------- phase B: gate (one block per batch) ----------------
    if ((i & 127) == 127) {        // last block of the group: likely last to pool
        if (tid == 0) {
            while (__hip_atomic_load(&ready[b], __ATOMIC_ACQUIRE, __HIP_MEMORY_SCOPE_AGENT)
                   < (unsigned)NC)
                __builtin_amdgcn_s_sleep(4);
        }
        __syncthreads();
        msh[tid] = __hip_atomic_load(&mean[b * NC + tid], __ATOMIC_RELAXED,
                                     __HIP_MEMORY_SCOPE_AGENT);
        __syncthreads();
        // h[r] = relu(b1[r] + mean[b,:] . w1[r,:]); wave w handles r = 4w..4w+3
        #pragma unroll
        for (int k = 0; k < 4; ++k) {
            const int r = wave * 4 + k;
            const vfloat4 wv = ((const vfloat4*)(w1 + r * NC))[lane];
            float p = msh[4 * lane + 0] * wv.x + msh[4 * lane + 1] * wv.y
                    + msh[4 * lane + 2] * wv.z + msh[4 * lane + 3] * wv.w;
            #pragma unroll
            for (int o = 32; o > 0; o >>= 1) p += __shfl_down(p, o, 64);
            if (lane == 0) hsh[r] = fmaxf(p + b1[r], 0.f);
        }
        __syncthreads();
        {
            const int c = tid;
            float a = b2[c];
            #pragma unroll
            for (int r = 0; r < NR; ++r) a += hsh[r] * w2[c * NR + r];
            float g = 1.0f / (1.0f + expf(-a));
            __hip_atomic_store(&gate[b * NC + c], g, __ATOMIC_RELAXED,
                               __HIP_MEMORY_SCOPE_AGENT);
        }
        __syncthreads();
        if (tid == 0)
            __hip_atomic_store(&gflag[b], 1u, __ATOMIC_RELEASE, __HIP_MEMORY_SCOPE_AGENT);
    }

    // ---------------- phase C: wait for gate, scale own planes ----------------
    if (tid == 0) {
        while (__hip_atomic_load(&gflag[b], __ATOMIC_ACQUIRE, __HIP_MEMORY_SCOPE_AGENT) == 0u)
            __builtin_amdgcn_s_sleep(4);
    }
    __syncthreads();
    #pragma unroll
    for (int q = 0; q < 2; ++q) {
        const int p = p0 + q;
        const float g = __hip_atomic_load(&gate[p], __ATOMIC_RELAXED,
                                          __HIP_MEMORY_SCOPE_AGENT);
        const size_t base = (size_t)p * PLANE;
        const vfloat4* xp = (const vfloat4*)(x + base);
        vfloat4* op = (vfloat4*)(out + base);
        #pragma unroll
        for (int h = 0; h < 2; ++h) {
            vfloat4 v[8];
            #pragma unroll
            for (int j = 0; j < 8; ++j) v[j] = xp[tid + (h * 8 + j) * 256];
            #pragma unroll
            for (int j = 0; j < 8; ++j) {
                vfloat4 w = v[j];
                w.x *= g; w.y *= g; w.z *= g; w.w *= g;
                __builtin_nontemporal_store(w, op + tid + (h * 8 + j) * 256);
            }
        }
    }
}

extern "C" void kernel_launch(void* const* d_in, const int* in_sizes, int n_in,
                              void* d_out, int out_size, void* d_ws, size_t ws_size,
                              hipStream_t stream) {
    const float* x  = (const float*)d_in[0];
    const float* w1 = (const float*)d_in[1];
    const float* b1 = (const float*)d_in[2];
    const float* w2 = (const float*)d_in[3];
    const float* b2 = (const float*)d_in[4];
    float* out = (float*)d_out;

    float* mean = (float*)d_ws;                    // 4096 floats
    float* gate = mean + NPLANES;                  // 4096 floats
    unsigned int* ready = (unsigned int*)(gate + NPLANES);  // 16 uints
    unsigned int* gflag = ready + NB;                       // 16 uints

    // Workspace is poisoned by the harness each iteration: the spin flags MUST
    // be zeroed inside the captured graph (memset node is graph-capture-legal).
    hipMemsetAsync(ready, 0, 2 * NB * sizeof(unsigned int), stream);

    fused_kernel<<<GRID, 256, 0, stream>>>(x, w1, b1, w2, b2, out,
                                           mean, gate, ready, gflag);
}

// Round 3
// 490.203 us; speedup vs baseline: 1.6075x; 1.6075x over previous
//
#include <hip/hip_runtime.h>
#include <math.h>

// x: [B=16, C=256, H=128, W=128] fp32; plane = 16384 elems; B*C = 4096 planes
#define PLANE 16384
#define NPLANES 4096
#define NB 16
#define NC 256
#define NR 16
#define GRID 2048          // 2 planes per block
#define SENTINEL 0xFFFFFFFFu  // NaN pattern: unreachable by finite means/sigmoid

typedef float vfloat4 __attribute__((ext_vector_type(4)));

__device__ __forceinline__ void pub_f32(float* p, float v) {
    // relaxed agent-scope store: single instruction to coherence point, NO L2 flush
    __hip_atomic_store((unsigned int*)p, __builtin_bit_cast(unsigned int, v),
                       __ATOMIC_RELAXED, __HIP_MEMORY_SCOPE_AGENT);
}
__device__ __forceinline__ float spin_f32(const float* p) {
    // relaxed agent-scope polling: NO cache invalidates; data IS the flag
    unsigned int u;
    while ((u = __hip_atomic_load((const unsigned int*)p, __ATOMIC_RELAXED,
                                  __HIP_MEMORY_SCOPE_AGENT)) == SENTINEL)
        __builtin_amdgcn_s_sleep(8);
    return __builtin_bit_cast(float, u);
}

// Single fused kernel, pipelined via SENTINEL-valued relaxed atomics (fence-free):
//   phase A: each block pools its 2 planes (same batch), publishes the 2 means
//   phase B: last block of each 128-block batch group spin-collects the 256
//            means (one per thread), computes the 256 gates, publishes them
//   phase C: every block spins on its 2 gate slots, then re-reads its OWN
//            2 planes (local-L2/L3 hit; round-2 FETCH proved full absorption)
//            and streams out with NT stores (don't evict x from L3).
__global__ __launch_bounds__(256, 8) void fused_kernel(
    const float* __restrict__ x,
    const float* __restrict__ w1, const float* __restrict__ b1,
    const float* __restrict__ w2, const float* __restrict__ b2,
    float* __restrict__ out,
    float* __restrict__ mean, float* __restrict__ gate)
{
    const int i   = blockIdx.x;
    const int tid = threadIdx.x;
    const int wave = tid >> 6, lane = tid & 63;
    const int p0 = i * 2;          // 2 consecutive planes, same batch
    const int b  = p0 >> 8;        // batch

    __shared__ float wsum[4];
    __shared__ float hsh[NR];
    __shared__ float msh[NC];
    __shared__ float gsh[2];

    // ---------------- phase A: pool both planes ----------------
    #pragma unroll
    for (int q = 0; q < 2; ++q) {
        const int p = p0 + q;
        const vfloat4* xp = (const vfloat4*)(x + (size_t)p * PLANE);
        float s = 0.f;
        #pragma unroll
        for (int h = 0; h < 2; ++h) {
            vfloat4 v[8];
            #pragma unroll
            for (int j = 0; j < 8; ++j) v[j] = xp[tid + (h * 8 + j) * 256];
            #pragma unroll
            for (int j = 0; j < 8; ++j) s += (v[j].x + v[j].y) + (v[j].z + v[j].w);
        }
        #pragma unroll
        for (int o = 32; o > 0; o >>= 1) s += __shfl_down(s, o, 64);
        if (lane == 0) wsum[wave] = s;
        __syncthreads();
        if (tid == 0) {
            float m = ((wsum[0] + wsum[1]) + (wsum[2] + wsum[3])) * (1.0f / (float)PLANE);
            pub_f32(&mean[p], m);   // value is its own ready-flag (sentinel scheme)
        }
        __syncthreads();   // wsum reuse
    }

    // ---------------- phase B: gate (last block of each 128-block group) ----------------
    if ((i & 127) == 127) {
        // 256 threads spin-collect the 256 means of this batch in parallel
        msh[tid] = spin_f32(&mean[b * NC + tid]);
        __syncthreads();
        // h[r] = relu(b1[r] + mean[b,:] . w1[r,:]); wave w handles r = 4w..4w+3
        #pragma unroll
        for (int k = 0; k < 4; ++k) {
            const int r = wave * 4 + k;
            const vfloat4 wv = ((const vfloat4*)(w1 + r * NC))[lane];
            float p = msh[4 * lane + 0] * wv.x + msh[4 * lane + 1] * wv.y
                    + msh[4 * lane + 2] * wv.z + msh[4 * lane + 3] * wv.w;
            #pragma unroll
            for (int o = 32; o > 0; o >>= 1) p += __shfl_down(p, o, 64);
            if (lane == 0) hsh[r] = fmaxf(p + b1[r], 0.f);
        }
        __syncthreads();
        {
            const int c = tid;
            float a = b2[c];
            #pragma unroll
            for (int r = 0; r < NR; ++r) a += hsh[r] * w2[c * NR + r];
            pub_f32(&gate[b * NC + c], 1.0f / (1.0f + expf(-a)));
        }
    }

    // ---------------- phase C: spin on own 2 gates, scale own 2 planes ----------------
    if (tid < 2) gsh[tid] = spin_f32(&gate[p0 + tid]);
    __syncthreads();
    #pragma unroll
    for (int q = 0; q < 2; ++q) {
        const float g = gsh[q];
        const size_t base = (size_t)(p0 + q) * PLANE;
        const vfloat4* xp = (const vfloat4*)(x + base);
        vfloat4* op = (vfloat4*)(out + base);
        #pragma unroll
        for (int h = 0; h < 2; ++h) {
            vfloat4 v[8];
            #pragma unroll
            for (int j = 0; j < 8; ++j) v[j] = xp[tid + (h * 8 + j) * 256];
            #pragma unroll
            for (int j = 0; j < 8; ++j) {
                vfloat4 w = v[j];
                w.x *= g; w.y *= g; w.z *= g; w.w *= g;
                __builtin_nontemporal_store(w, op + tid + (h * 8 + j) * 256);
            }
        }
    }
}

extern "C" void kernel_launch(void* const* d_in, const int* in_sizes, int n_in,
                              void* d_out, int out_size, void* d_ws, size_t ws_size,
                              hipStream_t stream) {
    const float* x  = (const float*)d_in[0];
    const float* w1 = (const float*)d_in[1];
    const float* b1 = (const float*)d_in[2];
    const float* w2 = (const float*)d_in[3];
    const float* b2 = (const float*)d_in[4];
    float* out = (float*)d_out;

    float* mean = (float*)d_ws;          // 4096 floats
    float* gate = mean + NPLANES;        // 4096 floats (contiguous with mean)

    // Reset mean+gate to the sentinel each iteration (graph-capture-legal).
    hipMemsetAsync(mean, 0xFF, 2 * NPLANES * sizeof(float), stream);

    fused_kernel<<<GRID, 256, 0, stream>>>(x, w1, b1, w2, b2, out, mean, gate);
}